// Round 6
// baseline (34267.905 us; speedup 1.0000x reference)
//
#include <hip/hip_runtime.h>
#include <math.h>

#define HID 100
#define SEQT 10
#define NOUT 5
#define BTILE 64      // batch elements per block
#define NTHR 256      // 4 waves
#define JPER 25       // output neurons per wave
#define JC 5          // chunk size
#define NCHUNK 5      // JPER / JC

// packed weight sizes (floats)
#define P0_FLOATS (20 * HID * 16)   // 32000: L0 hh, 16 floats per (chunk,k)
#define P1_FLOATS (20 * HID * 32)   // 64000: L1 ih+hh, 32 floats per (chunk,k)
#define CBP_FLOATS (20 * 88)        // 1760: per-chunk init data, 11 groups x 8
#define PACK_FLOATS (P0_FLOATS + P1_FLOATS + CBP_FLOATS)

__device__ __forceinline__ float sigm(float x) {
    float e = __expf(-x);
    return __builtin_amdgcn_rcpf(1.0f + e);
}
__device__ __forceinline__ float tanh_fast(float x) {
    float e = __expf(-2.0f * x);
    return fmaf(2.0f, __builtin_amdgcn_rcpf(1.0f + e), -1.0f);
}

// ---------------- weight repacking ----------------
// P0:  [chunk][k][16]  slots: 0-4 Whh0_r, 5-9 Whh0_z, 10-14 Whh0_n, 15 pad
// P1:  [chunk][k][32]  slots: 0-14 Wih1 r/z/n, 15 pad, 16-30 Whh1 r/z/n, 31 pad
// CBP: [chunk][11*8]   groups: 0 Wih0_r, 1 Wih0_z, 2 Wih0_n, 3 br0, 4 bz0,
//                      5 bin0, 6 bhn0, 7 br1, 8 bz1, 9 bin1, 10 bhn1 (5 used/8)
__global__ __launch_bounds__(256) void prep_kernel(
        const float* __restrict__ Wih0,
        const float* __restrict__ Whh0,
        const float* __restrict__ Wih1,
        const float* __restrict__ Whh1,
        const float* __restrict__ bih0, const float* __restrict__ bhh0,
        const float* __restrict__ bih1, const float* __restrict__ bhh1,
        float* __restrict__ ws) {
    int idx = blockIdx.x * blockDim.x + threadIdx.x;
    int stride = gridDim.x * blockDim.x;
    for (int i = idx; i < P0_FLOATS; i += stride) {
        int s = i & 15; int rest = i >> 4;
        int k = rest % HID; int c = rest / HID;
        float v = 0.0f;
        if (s < 15) { int g = s / JC, u = s % JC; v = Whh0[(g * HID + c * JC + u) * HID + k]; }
        ws[i] = v;
    }
    float* w1 = ws + P0_FLOATS;
    for (int i = idx; i < P1_FLOATS; i += stride) {
        int s = i & 31; int rest = i >> 5;
        int k = rest % HID; int c = rest / HID;
        float v = 0.0f;
        if (s < 15)                { int g = s / JC, u = s % JC;  v = Wih1[(g * HID + c * JC + u) * HID + k]; }
        else if (s >= 16 && s < 31){ int s2 = s - 16; int g = s2 / JC, u = s2 % JC; v = Whh1[(g * HID + c * JC + u) * HID + k]; }
        w1[i] = v;
    }
    float* cbp = ws + P0_FLOATS + P1_FLOATS;
    for (int i = idx; i < CBP_FLOATS; i += stride) {
        int c = i / 88; int r = i % 88;
        int G = r / 8; int u = r % 8;
        float v = 0.0f;
        if (u < 5) {
            int j = c * JC + u;
            switch (G) {
                case 0:  v = Wih0[j]; break;
                case 1:  v = Wih0[HID + j]; break;
                case 2:  v = Wih0[2 * HID + j]; break;
                case 3:  v = bih0[j] + bhh0[j]; break;
                case 4:  v = bih0[HID + j] + bhh0[HID + j]; break;
                case 5:  v = bih0[2 * HID + j]; break;
                case 6:  v = bhh0[2 * HID + j]; break;
                case 7:  v = bih1[j] + bhh1[j]; break;
                case 8:  v = bih1[HID + j] + bhh1[HID + j]; break;
                case 9:  v = bih1[2 * HID + j]; break;
                default: v = bhh1[2 * HID + j]; break;
            }
        }
        cbp[i] = v;
    }
}

// load group of 5 floats (stride-8 layout, 16B-aligned)
#define LOADG(dst, base, G) { \
    float4 _t4 = *(const float4*)((base) + (G) * 8); \
    dst[0] = _t4.x; dst[1] = _t4.y; dst[2] = _t4.z; dst[3] = _t4.w; \
    dst[4] = (base)[(G) * 8 + 4]; }

// all dst[] indices literal -> registers (rule #20 safe)
#define LDW4(dst, idx) { \
    dst[0] = wp[(idx) * 4 + 0]; dst[1] = wp[(idx) * 4 + 1]; \
    dst[2] = wp[(idx) * 4 + 2]; dst[3] = wp[(idx) * 4 + 3]; }

#define LDW8(dst, idx) { \
    dst[0] = wp[(idx) * 8 + 0]; dst[1] = wp[(idx) * 8 + 1]; \
    dst[2] = wp[(idx) * 8 + 2]; dst[3] = wp[(idx) * 8 + 3]; \
    dst[4] = wp[(idx) * 8 + 4]; dst[5] = wp[(idx) * 8 + 5]; \
    dst[6] = wp[(idx) * 8 + 6]; dst[7] = wp[(idx) * 8 + 7]; }

#define LDW8IH(dst, idx) { \
    dst[0] = wp[(idx) * 8 + 0]; dst[1] = wp[(idx) * 8 + 1]; \
    dst[2] = wp[(idx) * 8 + 2]; dst[3] = wp[(idx) * 8 + 3]; }

// L0 hh column: r slots 0-4, z slots 5-9, n slots 10-14 (of 16)
#define L0_STEP(W, hv) { \
    ar[0]=fmaf(hv,W[0].x,ar[0]); ar[1]=fmaf(hv,W[0].y,ar[1]); ar[2]=fmaf(hv,W[0].z,ar[2]); ar[3]=fmaf(hv,W[0].w,ar[3]); ar[4]=fmaf(hv,W[1].x,ar[4]); \
    az[0]=fmaf(hv,W[1].y,az[0]); az[1]=fmaf(hv,W[1].z,az[1]); az[2]=fmaf(hv,W[1].w,az[2]); az[3]=fmaf(hv,W[2].x,az[3]); az[4]=fmaf(hv,W[2].y,az[4]); \
    ahn[0]=fmaf(hv,W[2].z,ahn[0]); ahn[1]=fmaf(hv,W[2].w,ahn[1]); ahn[2]=fmaf(hv,W[3].x,ahn[2]); ahn[3]=fmaf(hv,W[3].y,ahn[3]); ahn[4]=fmaf(hv,W[3].z,ahn[4]); }

// L1 ih: slots 0-14 -> ar/az/ain
#define L1_IH(W, hv) { \
    ar[0]=fmaf(hv,W[0].x,ar[0]); ar[1]=fmaf(hv,W[0].y,ar[1]); ar[2]=fmaf(hv,W[0].z,ar[2]); ar[3]=fmaf(hv,W[0].w,ar[3]); ar[4]=fmaf(hv,W[1].x,ar[4]); \
    az[0]=fmaf(hv,W[1].y,az[0]); az[1]=fmaf(hv,W[1].z,az[1]); az[2]=fmaf(hv,W[1].w,az[2]); az[3]=fmaf(hv,W[2].x,az[3]); az[4]=fmaf(hv,W[2].y,az[4]); \
    ain[0]=fmaf(hv,W[2].z,ain[0]); ain[1]=fmaf(hv,W[2].w,ain[1]); ain[2]=fmaf(hv,W[3].x,ain[2]); ain[3]=fmaf(hv,W[3].y,ain[3]); ain[4]=fmaf(hv,W[3].z,ain[4]); }

// L1 hh: slots 16-30 -> ar/az/ahn
#define L1_HH(W, hv) { \
    ar[0]=fmaf(hv,W[4].x,ar[0]); ar[1]=fmaf(hv,W[4].y,ar[1]); ar[2]=fmaf(hv,W[4].z,ar[2]); ar[3]=fmaf(hv,W[4].w,ar[3]); ar[4]=fmaf(hv,W[5].x,ar[4]); \
    az[0]=fmaf(hv,W[5].y,az[0]); az[1]=fmaf(hv,W[5].z,az[1]); az[2]=fmaf(hv,W[5].w,az[2]); az[3]=fmaf(hv,W[6].x,az[3]); az[4]=fmaf(hv,W[6].y,az[4]); \
    ahn[0]=fmaf(hv,W[6].z,ahn[0]); ahn[1]=fmaf(hv,W[6].w,ahn[1]); ahn[2]=fmaf(hv,W[7].x,ahn[2]); ahn[3]=fmaf(hv,W[7].y,ahn[3]); ahn[4]=fmaf(hv,W[7].z,ahn[4]); }

#define GATES(c, hsrc) { \
    _Pragma("unroll") \
    for (int u = 0; u < JC; ++u) { \
        float r = sigm(ar[u]); \
        float z = sigm(az[u]); \
        float n = tanh_fast(fmaf(r, ahn[u], ain[u])); \
        float hold = (t > 0) ? hsrc[j0 + u][b] : 0.0f; \
        hnew[(c) * JC + u] = fmaf(z, hold - n, n); } }

// LDS caps us at 2 blocks/CU (= 2 waves/SIMD). Pin the allocator to exactly
// that occupancy so it gets the full 256-VGPR budget instead of squeezing
// into the 128-reg class (4 waves/SIMD capability we can never use) and
// spilling the pipeline buffers to scratch (R4/R5: 0.3-1.2 GB WRITE_SIZE).
__global__ __launch_bounds__(NTHR)
__attribute__((amdgpu_waves_per_eu(2, 2)))
void gru_packed(const float* __restrict__ x,
                const float* __restrict__ Wlin, const float* __restrict__ blin,
                const float* __restrict__ P0,
                const float* __restrict__ P1,
                const float* __restrict__ CBP,
                float* __restrict__ out) {
    __shared__ float h1s[HID][BTILE];   // 25.6 KB
    __shared__ float h2s[HID][BTILE];   // 25.6 KB
    __shared__ float rets[NOUT][BTILE];

    const int tid = threadIdx.x;
    const int b = tid & (BTILE - 1);
    const int q = tid >> 6;
    const int chunkbase = __builtin_amdgcn_readfirstlane(q * NCHUNK);
    const int blockStart = blockIdx.x * BTILE;

    // opaque zero: defeats uniformity analysis so weight loads stay VMEM
    // (global_load, vmcnt) instead of being scalarized to SMEM (lgkmcnt).
    int dz; asm volatile("v_mov_b32 %0, 0" : "=v"(dz));
    const float* P0v = P0 + dz;
    const float* P1v = P1 + dz;
    const float* CBv = CBP + dz;

    const float* xp = x + (size_t)(blockStart + b) * SEQT;

    for (int it = 0; it < NOUT; ++it) {
        for (int t = 0; t < SEQT; ++t) {
            const int s = it + t;
            // x from L2 (latency hidden against ~45K cy of FMA per (it,t))
            float xt = (s < SEQT) ? xp[s] : rets[s - SEQT][b];
            float hnew[JPER];

            // ================= layer 0 =================
            #pragma unroll
            for (int c = 0; c < NCHUNK; ++c) {
                const int chunkid = chunkbase + c;
                const int j0 = chunkid * JC;
                const float* cb = CBv + chunkid * 88;
                float wr[5], wz[5], wn[5], br[5], bz[5], bin[5], bhn[5];
                LOADG(wr, cb, 0); LOADG(wz, cb, 1); LOADG(wn, cb, 2);
                LOADG(br, cb, 3); LOADG(bz, cb, 4); LOADG(bin, cb, 5); LOADG(bhn, cb, 6);
                float ar[JC], az[JC], ain[JC], ahn[JC];
                #pragma unroll
                for (int u = 0; u < JC; ++u) {
                    ar[u]  = fmaf(xt, wr[u], br[u]);
                    az[u]  = fmaf(xt, wz[u], bz[u]);
                    ain[u] = fmaf(xt, wn[u], bin[u]);
                    ahn[u] = bhn[u];
                }
                if (t > 0) {
                    const float4* wp = (const float4*)P0v + (size_t)chunkid * HID * 4;
                    float4 A[4], B[4];
                    LDW4(A, 0); LDW4(B, 1);
                    #pragma unroll 1
                    for (int k = 0; k < HID; k += 2) {
                        float h0v = h1s[k][b];
                        L0_STEP(A, h0v);
                        LDW4(A, k + 2);            // overread at k=98 lands in P1 (allocated)
                        float h1v = h1s[k + 1][b];
                        L0_STEP(B, h1v);
                        LDW4(B, k + 3);
                    }
                }
                GATES(c, h1s);
            }
            __syncthreads();
            #pragma unroll
            for (int u = 0; u < JPER; ++u) h1s[chunkbase * JC + u][b] = hnew[u];
            __syncthreads();

            // ================= layer 1 =================
            #pragma unroll
            for (int c = 0; c < NCHUNK; ++c) {
                const int chunkid = chunkbase + c;
                const int j0 = chunkid * JC;
                const float* cb = CBv + chunkid * 88;
                float ar[JC], az[JC], ain[JC], ahn[JC];
                {
                    float br[5], bz[5], bin[5], bhn[5];
                    LOADG(br, cb, 7); LOADG(bz, cb, 8); LOADG(bin, cb, 9); LOADG(bhn, cb, 10);
                    #pragma unroll
                    for (int u = 0; u < JC; ++u) { ar[u]=br[u]; az[u]=bz[u]; ain[u]=bin[u]; ahn[u]=bhn[u]; }
                }
                const float4* wp = (const float4*)P1v + (size_t)chunkid * HID * 8;
                if (t > 0) {
                    float4 A[8], B[8];
                    LDW8(A, 0); LDW8(B, 1);
                    #pragma unroll 1
                    for (int k = 0; k < HID; k += 2) {
                        float g0 = h1s[k][b], e0 = h2s[k][b];
                        L1_IH(A, g0); L1_HH(A, e0);
                        LDW8(A, k + 2);            // overread at k=98 lands in CBP (allocated)
                        float g1 = h1s[k + 1][b], e1 = h2s[k + 1][b];
                        L1_IH(B, g1); L1_HH(B, e1);
                        LDW8(B, k + 3);
                    }
                } else {
                    // t == 0: h2 == 0, only ih half
                    float4 A[4], B[4];
                    LDW8IH(A, 0); LDW8IH(B, 1);
                    #pragma unroll 1
                    for (int k = 0; k < HID; k += 2) {
                        float g0 = h1s[k][b];
                        L1_IH(A, g0);
                        LDW8IH(A, k + 2);
                        float g1 = h1s[k + 1][b];
                        L1_IH(B, g1);
                        LDW8IH(B, k + 3);
                    }
                }
                GATES(c, h2s);
            }
            __syncthreads();
            #pragma unroll
            for (int u = 0; u < JPER; ++u) h2s[chunkbase * JC + u][b] = hnew[u];
            __syncthreads();
        }

        // output projection
        if (q == 0) {
            float acc = blin[0];
            const float4* wl = (const float4*)Wlin;
            #pragma unroll
            for (int kk = 0; kk < HID / 4; ++kk) {
                float4 wv = wl[kk];
                acc = fmaf(h2s[4 * kk][b],     wv.x, acc);
                acc = fmaf(h2s[4 * kk + 1][b], wv.y, acc);
                acc = fmaf(h2s[4 * kk + 2][b], wv.z, acc);
                acc = fmaf(h2s[4 * kk + 3][b], wv.w, acc);
            }
            out[(blockStart + b) * NOUT + it] = acc;
            rets[it][b] = acc;
        }
        __syncthreads();
    }
}

// -------- fallback (ws too small): generic scalar version --------
__global__ __launch_bounds__(NTHR, 2)
void gru_fallback(const float* __restrict__ x,
                  const float* __restrict__ Wih0, const float* __restrict__ Whh0,
                  const float* __restrict__ bih0, const float* __restrict__ bhh0,
                  const float* __restrict__ Wih1, const float* __restrict__ Whh1,
                  const float* __restrict__ bih1, const float* __restrict__ bhh1,
                  const float* __restrict__ Wlin, const float* __restrict__ blin,
                  float* __restrict__ out) {
    __shared__ float h1s[HID][BTILE];
    __shared__ float h2s[HID][BTILE];
    __shared__ float rets[NOUT][BTILE];
    const int tid = threadIdx.x;
    const int b = tid & (BTILE - 1);
    const int q = tid >> 6;
    const int chunkbase = __builtin_amdgcn_readfirstlane(q * NCHUNK);
    const int blockStart = blockIdx.x * BTILE;
    const float* xp = x + (size_t)(blockStart + b) * SEQT;
    for (int it = 0; it < NOUT; ++it) {
        for (int t = 0; t < SEQT; ++t) {
            const int s = it + t;
            float xt = (s < SEQT) ? xp[s] : rets[s - SEQT][b];
            float hnew[JPER];
            #pragma unroll
            for (int c = 0; c < NCHUNK; ++c) {
                const int j0 = (chunkbase + c) * JC;
                float ar[JC], az[JC], ain[JC], ahn[JC];
                #pragma unroll
                for (int u = 0; u < JC; ++u) {
                    int j = j0 + u;
                    ar[u]  = fmaf(xt, Wih0[j],           bih0[j] + bhh0[j]);
                    az[u]  = fmaf(xt, Wih0[HID + j],     bih0[HID + j] + bhh0[HID + j]);
                    ain[u] = fmaf(xt, Wih0[2 * HID + j], bih0[2 * HID + j]);
                    ahn[u] = bhh0[2 * HID + j];
                }
                if (t > 0) {
                    for (int k = 0; k < HID; ++k) {
                        const float hk = h1s[k][b];
                        #pragma unroll
                        for (int u = 0; u < JC; ++u) {
                            int j = j0 + u;
                            ar[u]  = fmaf(hk, Whh0[j * HID + k],             ar[u]);
                            az[u]  = fmaf(hk, Whh0[(HID + j) * HID + k],     az[u]);
                            ahn[u] = fmaf(hk, Whh0[(2 * HID + j) * HID + k], ahn[u]);
                        }
                    }
                }
                GATES(c, h1s);
            }
            __syncthreads();
            #pragma unroll
            for (int u = 0; u < JPER; ++u) h1s[chunkbase * JC + u][b] = hnew[u];
            __syncthreads();
            #pragma unroll
            for (int c = 0; c < NCHUNK; ++c) {
                const int j0 = (chunkbase + c) * JC;
                float ar[JC], az[JC], ain[JC], ahn[JC];
                #pragma unroll
                for (int u = 0; u < JC; ++u) {
                    int j = j0 + u;
                    ar[u]  = bih1[j] + bhh1[j];
                    az[u]  = bih1[HID + j] + bhh1[HID + j];
                    ain[u] = bih1[2 * HID + j];
                    ahn[u] = bhh1[2 * HID + j];
                }
                for (int k = 0; k < HID; ++k) {
                    const float h1k = h1s[k][b];
                    #pragma unroll
                    for (int u = 0; u < JC; ++u) {
                        int j = j0 + u;
                        ar[u]  = fmaf(h1k, Wih1[j * HID + k],             ar[u]);
                        az[u]  = fmaf(h1k, Wih1[(HID + j) * HID + k],     az[u]);
                        ain[u] = fmaf(h1k, Wih1[(2 * HID + j) * HID + k], ain[u]);
                    }
                    if (t > 0) {
                        const float h2k = h2s[k][b];
                        #pragma unroll
                        for (int u = 0; u < JC; ++u) {
                            int j = j0 + u;
                            ar[u]  = fmaf(h2k, Whh1[j * HID + k],             ar[u]);
                            az[u]  = fmaf(h2k, Whh1[(HID + j) * HID + k],     az[u]);
                            ahn[u] = fmaf(h2k, Whh1[(2 * HID + j) * HID + k], ahn[u]);
                        }
                    }
                }
                GATES(c, h2s);
            }
            __syncthreads();
            #pragma unroll
            for (int u = 0; u < JPER; ++u) h2s[chunkbase * JC + u][b] = hnew[u];
            __syncthreads();
        }
        if (q == 0) {
            float acc = blin[0];
            for (int k = 0; k < HID; ++k) acc = fmaf(h2s[k][b], Wlin[k], acc);
            out[(blockStart + b) * NOUT + it] = acc;
            rets[it][b] = acc;
        }
        __syncthreads();
    }
}

extern "C" void kernel_launch(void* const* d_in, const int* in_sizes, int n_in,
                              void* d_out, int out_size, void* d_ws, size_t ws_size,
                              hipStream_t stream) {
    const float* x    = (const float*)d_in[0];
    const float* Wih0 = (const float*)d_in[1];
    const float* Whh0 = (const float*)d_in[2];
    const float* bih0 = (const float*)d_in[3];
    const float* bhh0 = (const float*)d_in[4];
    const float* Wih1 = (const float*)d_in[5];
    const float* Whh1 = (const float*)d_in[6];
    const float* bih1 = (const float*)d_in[7];
    const float* bhh1 = (const float*)d_in[8];
    const float* Wlin = (const float*)d_in[9];
    const float* blin = (const float*)d_in[10];
    float* out = (float*)d_out;

    const int B = in_sizes[0] / SEQT;
    const int nblocks = B / BTILE;

    if (ws_size >= (size_t)PACK_FLOATS * sizeof(float)) {
        float* ws = (float*)d_ws;
        prep_kernel<<<90, 256, 0, stream>>>(Wih0, Whh0, Wih1, Whh1,
                                            bih0, bhh0, bih1, bhh1, ws);
        gru_packed<<<nblocks, NTHR, 0, stream>>>(
            x, Wlin, blin,
            ws, ws + P0_FLOATS, ws + P0_FLOATS + P1_FLOATS, out);
    } else {
        gru_fallback<<<nblocks, NTHR, 0, stream>>>(
            x, Wih0, Whh0, bih0, bhh0, Wih1, Whh1, bih1, bhh1, Wlin, blin, out);
    }
}

// Round 8
// 31912.073 us; speedup vs baseline: 1.0738x; 1.0738x over previous
//
#include <hip/hip_runtime.h>
#include <math.h>

#define HID 100
#define SEQT 10
#define NOUT 5
#define BTILE 64      // batch elements per block
#define NTHR 256      // 4 waves
#define JPER 25       // output neurons per wave
#define JC 5          // chunk size
#define NCHUNK 5      // JPER / JC

// packed weight sizes (floats)
#define P0_FLOATS (20 * HID * 16)   // 32000: L0 hh, 16 floats per (chunk,k)
#define P1_FLOATS (20 * HID * 32)   // 64000: L1 ih+hh, 32 floats per (chunk,k)
#define CBP_FLOATS (20 * 88)        // 1760: per-chunk init data, 11 groups x 8
#define PACK_FLOATS (P0_FLOATS + P1_FLOATS + CBP_FLOATS)

__device__ __forceinline__ float sigm(float x) {
    float e = __expf(-x);
    return __builtin_amdgcn_rcpf(1.0f + e);
}
__device__ __forceinline__ float tanh_fast(float x) {
    float e = __expf(-2.0f * x);
    return fmaf(2.0f, __builtin_amdgcn_rcpf(1.0f + e), -1.0f);
}

// ---------------- weight repacking ----------------
// P0:  [chunk][k][16]  slots: 0-4 Whh0_r, 5-9 Whh0_z, 10-14 Whh0_n, 15 pad
// P1:  [chunk][k][32]  slots: 0-14 Wih1 r/z/n, 15 pad, 16-30 Whh1 r/z/n, 31 pad
// CBP: [chunk][11*8]   groups: 0 Wih0_r, 1 Wih0_z, 2 Wih0_n, 3 br0, 4 bz0,
//                      5 bin0, 6 bhn0, 7 br1, 8 bz1, 9 bin1, 10 bhn1 (5 used/8)
__global__ __launch_bounds__(256) void prep_kernel(
        const float* __restrict__ Wih0,
        const float* __restrict__ Whh0,
        const float* __restrict__ Wih1,
        const float* __restrict__ Whh1,
        const float* __restrict__ bih0, const float* __restrict__ bhh0,
        const float* __restrict__ bih1, const float* __restrict__ bhh1,
        float* __restrict__ ws) {
    int idx = blockIdx.x * blockDim.x + threadIdx.x;
    int stride = gridDim.x * blockDim.x;
    for (int i = idx; i < P0_FLOATS; i += stride) {
        int s = i & 15; int rest = i >> 4;
        int k = rest % HID; int c = rest / HID;
        float v = 0.0f;
        if (s < 15) { int g = s / JC, u = s % JC; v = Whh0[(g * HID + c * JC + u) * HID + k]; }
        ws[i] = v;
    }
    float* w1 = ws + P0_FLOATS;
    for (int i = idx; i < P1_FLOATS; i += stride) {
        int s = i & 31; int rest = i >> 5;
        int k = rest % HID; int c = rest / HID;
        float v = 0.0f;
        if (s < 15)                { int g = s / JC, u = s % JC;  v = Wih1[(g * HID + c * JC + u) * HID + k]; }
        else if (s >= 16 && s < 31){ int s2 = s - 16; int g = s2 / JC, u = s2 % JC; v = Whh1[(g * HID + c * JC + u) * HID + k]; }
        w1[i] = v;
    }
    float* cbp = ws + P0_FLOATS + P1_FLOATS;
    for (int i = idx; i < CBP_FLOATS; i += stride) {
        int c = i / 88; int r = i % 88;
        int G = r / 8; int u = r % 8;
        float v = 0.0f;
        if (u < 5) {
            int j = c * JC + u;
            switch (G) {
                case 0:  v = Wih0[j]; break;
                case 1:  v = Wih0[HID + j]; break;
                case 2:  v = Wih0[2 * HID + j]; break;
                case 3:  v = bih0[j] + bhh0[j]; break;
                case 4:  v = bih0[HID + j] + bhh0[HID + j]; break;
                case 5:  v = bih0[2 * HID + j]; break;
                case 6:  v = bhh0[2 * HID + j]; break;
                case 7:  v = bih1[j] + bhh1[j]; break;
                case 8:  v = bih1[HID + j] + bhh1[HID + j]; break;
                case 9:  v = bih1[2 * HID + j]; break;
                default: v = bhh1[2 * HID + j]; break;
            }
        }
        cbp[i] = v;
    }
}

// load group of 5 floats (stride-8 layout, 16B-aligned)
#define LOADG(dst, base, G) { \
    float4 _t4 = *(const float4*)((base) + (G) * 8); \
    dst[0] = _t4.x; dst[1] = _t4.y; dst[2] = _t4.z; dst[3] = _t4.w; \
    dst[4] = (base)[(G) * 8 + 4]; }

// all dst[] indices literal -> registers (rule #20 safe)
// 16-float column slice at column kk, column stride 4 float4 (L0)
#define LDW4(dst, kk) { \
    dst[0] = wp[(kk) * 4 + 0]; dst[1] = wp[(kk) * 4 + 1]; \
    dst[2] = wp[(kk) * 4 + 2]; dst[3] = wp[(kk) * 4 + 3]; }

// 16-float half-column at column kk, column stride 8 float4 (L1 halves)
#define LDC16(dst, kk) { \
    dst[0] = wp[(kk) * 8 + 0]; dst[1] = wp[(kk) * 8 + 1]; \
    dst[2] = wp[(kk) * 8 + 2]; dst[3] = wp[(kk) * 8 + 3]; }

// 15-slot pattern r(0-4) z(5-9) n(10-14) over W[0..3]:
// r -> ar, z -> az, n -> ahn   (L0 hh column, and L1 hh half-column)
#define STEP_R_Z_HN(W, hv) { \
    ar[0]=fmaf(hv,W[0].x,ar[0]); ar[1]=fmaf(hv,W[0].y,ar[1]); ar[2]=fmaf(hv,W[0].z,ar[2]); ar[3]=fmaf(hv,W[0].w,ar[3]); ar[4]=fmaf(hv,W[1].x,ar[4]); \
    az[0]=fmaf(hv,W[1].y,az[0]); az[1]=fmaf(hv,W[1].z,az[1]); az[2]=fmaf(hv,W[1].w,az[2]); az[3]=fmaf(hv,W[2].x,az[3]); az[4]=fmaf(hv,W[2].y,az[4]); \
    ahn[0]=fmaf(hv,W[2].z,ahn[0]); ahn[1]=fmaf(hv,W[2].w,ahn[1]); ahn[2]=fmaf(hv,W[3].x,ahn[2]); ahn[3]=fmaf(hv,W[3].y,ahn[3]); ahn[4]=fmaf(hv,W[3].z,ahn[4]); }

// r -> ar, z -> az, n -> ain   (L1 ih half-column)
#define STEP_R_Z_IN(W, hv) { \
    ar[0]=fmaf(hv,W[0].x,ar[0]); ar[1]=fmaf(hv,W[0].y,ar[1]); ar[2]=fmaf(hv,W[0].z,ar[2]); ar[3]=fmaf(hv,W[0].w,ar[3]); ar[4]=fmaf(hv,W[1].x,ar[4]); \
    az[0]=fmaf(hv,W[1].y,az[0]); az[1]=fmaf(hv,W[1].z,az[1]); az[2]=fmaf(hv,W[1].w,az[2]); az[3]=fmaf(hv,W[2].x,az[3]); az[4]=fmaf(hv,W[2].y,az[4]); \
    ain[0]=fmaf(hv,W[2].z,ain[0]); ain[1]=fmaf(hv,W[2].w,ain[1]); ain[2]=fmaf(hv,W[3].x,ain[2]); ain[3]=fmaf(hv,W[3].y,ain[3]); ain[4]=fmaf(hv,W[3].z,ain[4]); }

#define GATES(c, hsrc) { \
    _Pragma("unroll") \
    for (int u = 0; u < JC; ++u) { \
        float r = sigm(ar[u]); \
        float z = sigm(az[u]); \
        float n = tanh_fast(fmaf(r, ahn[u], ain[u])); \
        float hold = (t > 0) ? hsrc[j0 + u][b] : 0.0f; \
        hnew[(c) * JC + u] = fmaf(z, hold - n, n); } }

// Register budget is the whole game (R4-R6): keep peak live < 128 so the
// allocator's 4-wave class fits with ZERO spill. L1 is split into an
// ih-pass and an hh-pass so weight buffers are A[4]+B[4]=32 regs per pass.
__global__ __launch_bounds__(NTHR, 2)
void gru_packed(const float* __restrict__ x,
                const float* __restrict__ Wlin, const float* __restrict__ blin,
                const float* __restrict__ P0,
                const float* __restrict__ P1,
                const float* __restrict__ CBP,
                float* __restrict__ out) {
    __shared__ float h1s[HID][BTILE];   // 25.6 KB
    __shared__ float h2s[HID][BTILE];   // 25.6 KB
    __shared__ float rets[NOUT][BTILE];

    const int tid = threadIdx.x;
    const int b = tid & (BTILE - 1);
    const int q = tid >> 6;
    const int chunkbase = __builtin_amdgcn_readfirstlane(q * NCHUNK);
    const int blockStart = blockIdx.x * BTILE;

    // opaque zero: defeats uniformity analysis so weight loads stay VMEM
    // (global_load, vmcnt) instead of being scalarized to SMEM (lgkmcnt).
    int dz; asm volatile("v_mov_b32 %0, 0" : "=v"(dz));
    const float* P0v = P0 + dz;
    const float* P1v = P1 + dz;
    const float* CBv = CBP + dz;

    const float* xp = x + (size_t)(blockStart + b) * SEQT;

    for (int it = 0; it < NOUT; ++it) {
        for (int t = 0; t < SEQT; ++t) {
            const int s = it + t;
            float xt = (s < SEQT) ? xp[s] : rets[s - SEQT][b];
            float hnew[JPER];

            // ================= layer 0 =================
            #pragma unroll
            for (int c = 0; c < NCHUNK; ++c) {
                const int chunkid = chunkbase + c;
                const int j0 = chunkid * JC;
                const float* cb = CBv + chunkid * 88;
                float ar[JC], az[JC], ain[JC], ahn[JC];
                {
                    float wr[5], wz[5], wn[5], br[5], bz[5], bin[5], bhn[5];
                    LOADG(wr, cb, 0); LOADG(wz, cb, 1); LOADG(wn, cb, 2);
                    LOADG(br, cb, 3); LOADG(bz, cb, 4); LOADG(bin, cb, 5); LOADG(bhn, cb, 6);
                    #pragma unroll
                    for (int u = 0; u < JC; ++u) {
                        ar[u]  = fmaf(xt, wr[u], br[u]);
                        az[u]  = fmaf(xt, wz[u], bz[u]);
                        ain[u] = fmaf(xt, wn[u], bin[u]);
                        ahn[u] = bhn[u];
                    }
                }
                if (t > 0) {
                    const float4* wp = (const float4*)P0v + (size_t)chunkid * HID * 4;
                    float4 A[4], B[4];
                    LDW4(A, 0); LDW4(B, 1);
                    #pragma unroll 1
                    for (int k = 0; k < HID; k += 2) {
                        float h0v = h1s[k][b];
                        STEP_R_Z_HN(A, h0v);
                        LDW4(A, k + 2);            // overread at k=98 lands in P1 (allocated)
                        float h1v = h1s[k + 1][b];
                        STEP_R_Z_HN(B, h1v);
                        LDW4(B, k + 3);
                    }
                }
                GATES(c, h1s);
            }
            __syncthreads();
            #pragma unroll
            for (int u = 0; u < JPER; ++u) h1s[chunkbase * JC + u][b] = hnew[u];
            __syncthreads();

            // ================= layer 1 =================
            #pragma unroll
            for (int c = 0; c < NCHUNK; ++c) {
                const int chunkid = chunkbase + c;
                const int j0 = chunkid * JC;
                const float* cb = CBv + chunkid * 88;
                float ar[JC], az[JC], ain[JC], ahn[JC];
                {
                    float br[5], bz[5], bin[5], bhn[5];
                    LOADG(br, cb, 7); LOADG(bz, cb, 8); LOADG(bin, cb, 9); LOADG(bhn, cb, 10);
                    #pragma unroll
                    for (int u = 0; u < JC; ++u) { ar[u]=br[u]; az[u]=bz[u]; ain[u]=bin[u]; ahn[u]=bhn[u]; }
                }
                // ---- pass 1: ih half-columns (slots 0-15) against h1 ----
                {
                    const float4* wp = (const float4*)P1v + (size_t)chunkid * HID * 8;
                    float4 A[4], B[4];
                    LDC16(A, 0); LDC16(B, 1);
                    #pragma unroll 1
                    for (int k = 0; k < HID; k += 2) {
                        float g0 = h1s[k][b];
                        STEP_R_Z_IN(A, g0);
                        LDC16(A, k + 2);           // overread: next chunk / CBP (allocated)
                        float g1 = h1s[k + 1][b];
                        STEP_R_Z_IN(B, g1);
                        LDC16(B, k + 3);
                    }
                }
                // ---- pass 2: hh half-columns (slots 16-31) against h2 ----
                if (t > 0) {
                    const float4* wp = (const float4*)P1v + (size_t)chunkid * HID * 8 + 4;
                    float4 A[4], B[4];
                    LDC16(A, 0); LDC16(B, 1);
                    #pragma unroll 1
                    for (int k = 0; k < HID; k += 2) {
                        float e0 = h2s[k][b];
                        STEP_R_Z_HN(A, e0);
                        LDC16(A, k + 2);
                        float e1 = h2s[k + 1][b];
                        STEP_R_Z_HN(B, e1);
                        LDC16(B, k + 3);
                    }
                }
                GATES(c, h2s);
            }
            __syncthreads();
            #pragma unroll
            for (int u = 0; u < JPER; ++u) h2s[chunkbase * JC + u][b] = hnew[u];
            __syncthreads();
        }

        // output projection
        if (q == 0) {
            float acc = blin[0];
            const float4* wl = (const float4*)Wlin;
            #pragma unroll
            for (int kk = 0; kk < HID / 4; ++kk) {
                float4 wv = wl[kk];
                acc = fmaf(h2s[4 * kk][b],     wv.x, acc);
                acc = fmaf(h2s[4 * kk + 1][b], wv.y, acc);
                acc = fmaf(h2s[4 * kk + 2][b], wv.z, acc);
                acc = fmaf(h2s[4 * kk + 3][b], wv.w, acc);
            }
            out[(blockStart + b) * NOUT + it] = acc;
            rets[it][b] = acc;
        }
        __syncthreads();
    }
}

// -------- fallback (ws too small): generic scalar version --------
__global__ __launch_bounds__(NTHR, 2)
void gru_fallback(const float* __restrict__ x,
                  const float* __restrict__ Wih0, const float* __restrict__ Whh0,
                  const float* __restrict__ bih0, const float* __restrict__ bhh0,
                  const float* __restrict__ Wih1, const float* __restrict__ Whh1,
                  const float* __restrict__ bih1, const float* __restrict__ bhh1,
                  const float* __restrict__ Wlin, const float* __restrict__ blin,
                  float* __restrict__ out) {
    __shared__ float h1s[HID][BTILE];
    __shared__ float h2s[HID][BTILE];
    __shared__ float rets[NOUT][BTILE];
    const int tid = threadIdx.x;
    const int b = tid & (BTILE - 1);
    const int q = tid >> 6;
    const int chunkbase = __builtin_amdgcn_readfirstlane(q * NCHUNK);
    const int blockStart = blockIdx.x * BTILE;
    const float* xp = x + (size_t)(blockStart + b) * SEQT;
    for (int it = 0; it < NOUT; ++it) {
        for (int t = 0; t < SEQT; ++t) {
            const int s = it + t;
            float xt = (s < SEQT) ? xp[s] : rets[s - SEQT][b];
            float hnew[JPER];
            #pragma unroll
            for (int c = 0; c < NCHUNK; ++c) {
                const int j0 = (chunkbase + c) * JC;
                float ar[JC], az[JC], ain[JC], ahn[JC];
                #pragma unroll
                for (int u = 0; u < JC; ++u) {
                    int j = j0 + u;
                    ar[u]  = fmaf(xt, Wih0[j],           bih0[j] + bhh0[j]);
                    az[u]  = fmaf(xt, Wih0[HID + j],     bih0[HID + j] + bhh0[HID + j]);
                    ain[u] = fmaf(xt, Wih0[2 * HID + j], bih0[2 * HID + j]);
                    ahn[u] = bhh0[2 * HID + j];
                }
                if (t > 0) {
                    for (int k = 0; k < HID; ++k) {
                        const float hk = h1s[k][b];
                        #pragma unroll
                        for (int u = 0; u < JC; ++u) {
                            int j = j0 + u;
                            ar[u]  = fmaf(hk, Whh0[j * HID + k],             ar[u]);
                            az[u]  = fmaf(hk, Whh0[(HID + j) * HID + k],     az[u]);
                            ahn[u] = fmaf(hk, Whh0[(2 * HID + j) * HID + k], ahn[u]);
                        }
                    }
                }
                GATES(c, h1s);
            }
            __syncthreads();
            #pragma unroll
            for (int u = 0; u < JPER; ++u) h1s[chunkbase * JC + u][b] = hnew[u];
            __syncthreads();
            #pragma unroll
            for (int c = 0; c < NCHUNK; ++c) {
                const int j0 = (chunkbase + c) * JC;
                float ar[JC], az[JC], ain[JC], ahn[JC];
                #pragma unroll
                for (int u = 0; u < JC; ++u) {
                    int j = j0 + u;
                    ar[u]  = bih1[j] + bhh1[j];
                    az[u]  = bih1[HID + j] + bhh1[HID + j];
                    ain[u] = bih1[2 * HID + j];
                    ahn[u] = bhh1[2 * HID + j];
                }
                for (int k = 0; k < HID; ++k) {
                    const float h1k = h1s[k][b];
                    #pragma unroll
                    for (int u = 0; u < JC; ++u) {
                        int j = j0 + u;
                        ar[u]  = fmaf(h1k, Wih1[j * HID + k],             ar[u]);
                        az[u]  = fmaf(h1k, Wih1[(HID + j) * HID + k],     az[u]);
                        ain[u] = fmaf(h1k, Wih1[(2 * HID + j) * HID + k], ain[u]);
                    }
                    if (t > 0) {
                        const float h2k = h2s[k][b];
                        #pragma unroll
                        for (int u = 0; u < JC; ++u) {
                            int j = j0 + u;
                            ar[u]  = fmaf(h2k, Whh1[j * HID + k],             ar[u]);
                            az[u]  = fmaf(h2k, Whh1[(HID + j) * HID + k],     az[u]);
                            ahn[u] = fmaf(h2k, Whh1[(2 * HID + j) * HID + k], ahn[u]);
                        }
                    }
                }
                GATES(c, h2s);
            }
            __syncthreads();
            #pragma unroll
            for (int u = 0; u < JPER; ++u) h2s[chunkbase * JC + u][b] = hnew[u];
            __syncthreads();
        }
        if (q == 0) {
            float acc = blin[0];
            for (int k = 0; k < HID; ++k) acc = fmaf(h2s[k][b], Wlin[k], acc);
            out[(blockStart + b) * NOUT + it] = acc;
            rets[it][b] = acc;
        }
        __syncthreads();
    }
}

extern "C" void kernel_launch(void* const* d_in, const int* in_sizes, int n_in,
                              void* d_out, int out_size, void* d_ws, size_t ws_size,
                              hipStream_t stream) {
    const float* x    = (const float*)d_in[0];
    const float* Wih0 = (const float*)d_in[1];
    const float* Whh0 = (const float*)d_in[2];
    const float* bih0 = (const float*)d_in[3];
    const float* bhh0 = (const float*)d_in[4];
    const float* Wih1 = (const float*)d_in[5];
    const float* Whh1 = (const float*)d_in[6];
    const float* bih1 = (const float*)d_in[7];
    const float* bhh1 = (const float*)d_in[8];
    const float* Wlin = (const float*)d_in[9];
    const float* blin = (const float*)d_in[10];
    float* out = (float*)d_out;

    const int B = in_sizes[0] / SEQT;
    const int nblocks = B / BTILE;

    if (ws_size >= (size_t)PACK_FLOATS * sizeof(float)) {
        float* ws = (float*)d_ws;
        prep_kernel<<<90, 256, 0, stream>>>(Wih0, Whh0, Wih1, Whh1,
                                            bih0, bhh0, bih1, bhh1, ws);
        gru_packed<<<nblocks, NTHR, 0, stream>>>(
            x, Wlin, blin,
            ws, ws + P0_FLOATS, ws + P0_FLOATS + P1_FLOATS, out);
    } else {
        gru_fallback<<<nblocks, NTHR, 0, stream>>>(
            x, Wih0, Whh0, bih0, bhh0, Wih1, Whh1, bih1, bhh1, Wlin, blin, out);
    }
}